// Round 6
// baseline (109.496 us; speedup 1.0000x reference)
//
#include <hip/hip_runtime.h>

// out[b,o] = sum_k w[idx[b],o,k] * x[b,k];  B=2048, C=64, IN=OUT=512.
//
// r12: r11 (-2.7us, gathers-first prologue) confirmed ramp costs matter.
// Remaining model gap: 512 blocks each pay ~1us idx-scan ramp + per-tile
// drain at a 2-block-shared CU slice. Restructure: grid 256 (TPB=8 tiles,
// 1 block/CU), 3 staging buffers (LDS 96+4+6=106KB, fine at 1 block/CU):
//   * half the chip-wide prologues (256 idx scans, not 512);
//   * prologue primes 3 tiles (96KB in flight immediately);
//   * stage(t+2) issues at TILE START (B[(t-1)%3] provably free after the
//     end-of-tile-(t-1) barrier) -> stream never below 2 tiles in flight;
//   * whole-CU BW per block: per-tile drain ~1.3us, 8 tiles ~10.4us.
// Waits: prologue vmcnt(24)=gathers landed (3 stages flying), vm16+bar =
// stage(0) landed; per-tile vm8+bar = stage(t+1) landed/(t+2) flying;
// vm0 only before the last tile. Rest = r11: contiguous W stream,
// source-side 16B-granule XOR swizzle, XCD-bijective swizzle, gathers-
// first FIFO order, xf in regs, lgkm-only reduce barriers, rare n>32 /
// n>64 slow paths.

constexpr int Bsz  = 2048;
constexpr int Ccnt = 64;
constexpr int INF  = 512;
constexpr int OUTF = 512;
constexpr int THREADS = 256;   // 4 waves = 4 K-quarters
constexpr int OT  = 16;        // out rows per staged tile
constexpr int TPB = 8;         // consecutive tiles per block
constexpr int NBUF = 3;        // staging depth
constexpr int NBLK = Ccnt * (OUTF / (OT * TPB));   // 256

typedef __attribute__((ext_vector_type(8))) short bf16x8;
typedef __attribute__((ext_vector_type(4))) float f32x4;

#if __has_builtin(__builtin_amdgcn_cvt_pk_bf16_f32)
typedef __attribute__((ext_vector_type(2))) __bf16 bf16x2_t;
__device__ __forceinline__ int cvt2i(float a, float b) {
    union { bf16x2_t v; int i; } u;
    u.v = __builtin_amdgcn_cvt_pk_bf16_f32(a, b);
    return u.i;
}
#else
__device__ __forceinline__ unsigned f2bf(float f) {
    union { float f; unsigned u; } v; v.f = f;
    return (v.u + 0x7FFFu + ((v.u >> 16) & 1u)) >> 16;   // RNE
}
__device__ __forceinline__ int cvt2i(float a, float b) {
    return (int)(f2bf(a) | (f2bf(b) << 16));
}
#endif

__device__ __forceinline__ bf16x8 cvt8(float4 a, float4 b) {
    union { bf16x8 v; int i[4]; } u;
    u.i[0] = cvt2i(a.x, a.y);
    u.i[1] = cvt2i(a.z, a.w);
    u.i[2] = cvt2i(b.x, b.y);
    u.i[3] = cvt2i(b.z, b.w);
    return u.v;
}

// async 16B/lane global -> LDS (dest = wave-uniform base + lane*16)
__device__ __forceinline__ void gld_lds16(const float* g, float* l) {
    __builtin_amdgcn_global_load_lds(
        (const __attribute__((address_space(1))) float*)g,
        (__attribute__((address_space(3))) float*)l, 16, 0, 0);
}

// workgroup barrier that does NOT touch vmcnt (keeps staging in flight)
__device__ __forceinline__ void barrier_lgkm() {
    asm volatile("s_waitcnt lgkmcnt(0)" ::: "memory");
    __builtin_amdgcn_s_barrier();
    asm volatile("" ::: "memory");
}

// counted-vmcnt barriers: oldest stage landed, newer ones keep flying
__device__ __forceinline__ void vm16_barrier() {
    asm volatile("s_waitcnt vmcnt(16)" ::: "memory");
    __builtin_amdgcn_sched_barrier(0);
    __builtin_amdgcn_s_barrier();
    asm volatile("" ::: "memory");
}
__device__ __forceinline__ void vm8_barrier() {
    asm volatile("s_waitcnt vmcnt(8)" ::: "memory");
    __builtin_amdgcn_sched_barrier(0);
    __builtin_amdgcn_s_barrier();
    asm volatile("" ::: "memory");
}
__device__ __forceinline__ void vm0_barrier() {
    asm volatile("s_waitcnt vmcnt(0)" ::: "memory");
    __builtin_amdgcn_sched_barrier(0);
    __builtin_amdgcn_s_barrier();
    asm volatile("" ::: "memory");
}

// stage one 16x512 f32 tile (contiguous 32KB) into LDS, 8 x 1KB insts/wave.
// Element (r,k) lands at dst[r*512 + (((k>>2) ^ (r&7)))*4 + (k&3)] (16B-
// granule XOR swizzle applied on the SOURCE side within 128B lines ->
// coalescing identical to a linear copy; reads de-swizzle with same XOR).
__device__ __forceinline__ void stage_tile(const float* wt, float* dst,
                                           int wave, int lane) {
#pragma unroll
    for (int i = 0; i < 8; ++i) {
        const int inst = wave * 8 + i;
        const int r = inst >> 1;
        const int h = inst & 1;
        const int p = r & 7;
        const float* src = wt + (size_t)r * INF + (h * 64 + (lane ^ p)) * 4;
        gld_lds16(src, dst + inst * 256);
    }
}

// cross-wave K-reduce + store, rounds of 2 groups (fixed order ->
// deterministic). lgkm-only barriers: never drains in-flight staging.
__device__ __forceinline__ void kreduce_store(
        const f32x4* acc, int ng, int s0, int n, int o0,
        int wave, int lane, int mrow, int quad,
        const unsigned short* list, float (*red)[3][4][64],
        float* __restrict__ out) {
#pragma unroll
    for (int r0 = 0; r0 < 4; r0 += 2) {
        if (r0 < ng) {                       // uniform across block
            if (wave != 0) {
#pragma unroll
                for (int g = 0; g < 2; ++g) {
                    if (r0 + g < ng) {
#pragma unroll
                        for (int j = 0; j < 4; ++j)
                            red[g][wave - 1][j][lane] = acc[r0 + g][j];
                    }
                }
            }
            barrier_lgkm();
            if (wave == 0) {
#pragma unroll
                for (int g = 0; g < 2; ++g) {
                    if (r0 + g < ng) {
                        const int s = s0 + (r0 + g) * 16 + mrow;
                        if (s < n) {
                            f32x4 a = acc[r0 + g];
#pragma unroll
                            for (int wv2 = 0; wv2 < 3; ++wv2)
#pragma unroll
                                for (int j = 0; j < 4; ++j)
                                    a[j] += red[g][wv2][j][lane];
                            float* dst = out + (size_t)list[s] * OUTF
                                             + o0 + quad * 4;
                            *(float4*)dst = make_float4(a[0], a[1], a[2], a[3]);
                        }
                    }
                }
            }
            barrier_lgkm();                  // red reusable next round
        }
    }
}

__global__ __launch_bounds__(THREADS, 1)
void switching_linear_kernel(const float* __restrict__ x,
                             const int* __restrict__ idx,
                             const float* __restrict__ w,
                             float* __restrict__ out) {
    __shared__ float Wl[NBUF][OT * INF];    // 96 KB triple-buffered W tile
    __shared__ unsigned short list[Bsz];    // 4 KB
    __shared__ int ls_n;
    __shared__ float red[2][3][4][64];      // 6 KB (rounds of 2 groups)

    const int tid  = threadIdx.x;
    const int wave = tid >> 6;
    const int lane = tid & 63;

    // XCD-bijective swizzle: the 4 blocks of a class land on one XCD
    const int bid   = ((int)blockIdx.x & 7) * (NBLK / 8) + ((int)blockIdx.x >> 3);
    const int c     = bid >> 2;                 // class (4 row-groups each)
    const int obase = (bid & 3) * (OT * TPB);   // first of 128 contiguous rows

    if (tid == 0) ls_n = 0;
    __syncthreads();   // nothing in flight yet

    // ---- idx scan + list build ----
    int my[8];
#pragma unroll
    for (int i = 0; i < 8; ++i) my[i] = idx[tid + i * THREADS];
#pragma unroll
    for (int i = 0; i < 8; ++i)
        if (my[i] == c) list[atomicAdd(&ls_n, 1)] = (unsigned short)(tid + i * THREADS);

    __syncthreads();   // list complete (drains idx loads; nothing else)
    const int n = ls_n;
    if (n == 0) return;             // uniform; nothing in flight

    const int mrow = lane & 15;   // A row / C col
    const int quad = lane >> 4;   // k segment / C row group
    const int k0   = wave * (INF / 4);
    const int p    = mrow & 7;
    const float* wc = w + (size_t)c * OUTF * INF + (size_t)obase * INF;

    const int ng0 = (n >= 64) ? 4 : ((n + 15) >> 4);
    const int ngp = ng0 < 2 ? ng0 : 2;   // groups preloaded before staging

    // ---- prologue: gathers FIRST (oldest in FIFO), then three stages ----
    float4 raw[2][8];               // ngp groups of raw x data (<=64 VGPR)
#pragma unroll
    for (int g = 0; g < 2; ++g) {
        if (g < ngp) {              // block-uniform -> per-wave count uniform
            const int s  = g * 16 + mrow;
            const int sc = s < n ? s : n - 1;
            const float* bp = x + (size_t)list[sc] * INF + k0 + quad * 8;
#pragma unroll
            for (int i = 0; i < 4; ++i) {
                raw[g][2 * i]     = *(const float4*)(bp + i * 32);
                raw[g][2 * i + 1] = *(const float4*)(bp + i * 32 + 4);
            }
        }
    }
    __builtin_amdgcn_sched_barrier(0);   // pin: gathers precede stage issues

    stage_tile(wc,                      Wl[0], wave, lane);   // stage(0)
    stage_tile(wc + (size_t)OT * INF,   Wl[1], wave, lane);   // stage(1)
    stage_tile(wc + (size_t)2*OT * INF, Wl[2], wave, lane);   // stage(2)

    asm volatile("s_waitcnt vmcnt(24)" ::: "memory");  // gathers landed;
    __builtin_amdgcn_sched_barrier(0);                 // 3 stages flying

    bf16x8 xf[4][4];                // chunk-0 x fragments, reused by all tiles
#pragma unroll
    for (int g = 0; g < 2; ++g) {
        if (g < ngp) {
#pragma unroll
            for (int i = 0; i < 4; ++i)
                xf[g][i] = cvt8(raw[g][2 * i], raw[g][2 * i + 1]);
        }
    }
    if (ng0 > 2) {   // rare (n>32): gather remaining groups; compiler waits
#pragma unroll       // drain the stages (acceptable on this path)
        for (int g = 2; g < 4; ++g) {
            if (g < ng0) {
                const int s  = g * 16 + mrow;
                const int sc = s < n ? s : n - 1;
                const float* bp = x + (size_t)list[sc] * INF + k0 + quad * 8;
#pragma unroll
                for (int i = 0; i < 4; ++i) {
                    float4 b0 = *(const float4*)(bp + i * 32);
                    float4 b1 = *(const float4*)(bp + i * 32 + 4);
                    xf[g][i] = cvt8(b0, b1);
                }
            }
        }
    }

    vm16_barrier();  // stage(0) landed block-wide; stages(1,2) keep flying

    for (int ot = 0; ot < TPB; ++ot) {
        // B[(ot-1)%3] is free (all waves passed end-of-tile-(ot-1) barrier
        // after their reads) == target of stage(ot+2). Issue EARLY.
        if (ot >= 1 && ot + 2 < TPB)
            stage_tile(wc + (size_t)((ot + 2) * OT) * INF,
                       Wl[(ot + 2) % NBUF], wave, lane);

        const float* Wb = Wl[ot % NBUF];
        const int o0 = obase + ot * OT;

        // A-fragments for this tile (LDS -> regs, lgkm domain only)
        bf16x8 wf[4];
#pragma unroll
        for (int t = 0; t < 4; ++t) {
            const int gb = (k0 >> 2) + t * 8 + quad * 2;   // granule in row
            float4 a0 = *(const float4*)&Wb[mrow * INF + ((gb)     ^ p) * 4];
            float4 a1 = *(const float4*)&Wb[mrow * INF + ((gb + 1) ^ p) * 4];
            wf[t] = cvt8(a0, a1);
        }

        // ---- chunk 0: pure register MFMA (no vmem -> stage stays in flight)
        {
            f32x4 acc[4];
#pragma unroll
            for (int g = 0; g < 4; ++g) acc[g] = (f32x4){0.f, 0.f, 0.f, 0.f};
#pragma unroll
            for (int g = 0; g < 4; ++g) {
                if (g < ng0) {
#pragma unroll
                    for (int i = 0; i < 4; ++i)
                        acc[g] = __builtin_amdgcn_mfma_f32_16x16x32_bf16(
                                     wf[i], xf[g][i], acc[g], 0, 0, 0);
                }
            }
            kreduce_store(acc, ng0, 0, n, o0, wave, lane, mrow, quad,
                          list, red, out);
        }

        // ---- rare slow path: chunks beyond 64 samples (gathers in-loop) ----
        for (int s0 = 64; s0 < n; s0 += 64) {
            const int rem = n - s0;
            const int ng  = rem >= 64 ? 4 : (rem + 15) >> 4;

            f32x4 acc[4];
#pragma unroll
            for (int g = 0; g < 4; ++g) acc[g] = (f32x4){0.f, 0.f, 0.f, 0.f};
#pragma unroll
            for (int g = 0; g < 4; ++g) {
                if (g < ng) {
                    const int s  = s0 + g * 16 + mrow;
                    const int sc = s < n ? s : n - 1;
                    const float* bp = x + (size_t)list[sc] * INF + k0 + quad * 8;
#pragma unroll
                    for (int i = 0; i < 4; ++i) {
                        float4 b0 = *(const float4*)(bp + i * 32);
                        float4 b1 = *(const float4*)(bp + i * 32 + 4);
                        acc[g] = __builtin_amdgcn_mfma_f32_16x16x32_bf16(
                                     wf[i], cvt8(b0, b1), acc[g], 0, 0, 0);
                    }
                }
            }
            kreduce_store(acc, ng, s0, n, o0, wave, lane, mrow, quad,
                          list, red, out);
        }

        // end-of-tile: stage(ot+1) must have landed; newer stage keeps flying
        if (ot + 1 < TPB) {
            if (ot + 2 < TPB) vm8_barrier();   // stage(ot+2) (8 ops) flying
            else              vm0_barrier();   // final stage: full drain
        }
    }
}

extern "C" void kernel_launch(void* const* d_in, const int* in_sizes, int n_in,
                              void* d_out, int out_size, void* d_ws, size_t ws_size,
                              hipStream_t stream) {
    const float* x   = (const float*)d_in[0];
    const int*   idx = (const int*)d_in[1];
    const float* w   = (const float*)d_in[2];
    float* out = (float*)d_out;

    switching_linear_kernel<<<dim3(NBLK), dim3(THREADS), 0, stream>>>(x, idx, w, out);
}

// Round 7
// 106.401 us; speedup vs baseline: 1.0291x; 1.0291x over previous
//
#include <hip/hip_runtime.h>

// out[b,o] = sum_k w[idx[b],o,k] * x[b,k];  B=2048, C=64, IN=OUT=512.
//
// r13: r12 (grid 256, 1 block/CU, deep buffer) REGRESSED +7us: 1 wave/SIMD
// and no co-resident block -> every compute/reduce gap exposed BW-idle
// time. Inter-block TLP is the pipeline here. Revert to r11's shell
// (grid 512, 2 blocks/CU, TPB=4, NBUF=2) and remove its biggest serial
// cost instead: the cross-wave K-reduce (4 lgkm barriers + red LDS +
// wave0-serial adds per tile). New decomposition: each wave owns ONE
// 16-sample group with FULL K=512 (ng0=ceil(n/16)~2-3 active waves);
// acc is complete per wave -> NO reduce, NO red LDS, direct f32x4 store.
// Per tile: 2 barriers (lgkm read-fence before buffer overwrite + counted
// vm8 handoff) instead of 5. xf gathered once at full K (32 float4,
// gathers-FIRST FIFO order; vmcnt(16) = gathers landed, both stages
// flying). W-frag/x-frag per-chunk layouts identical to r11 (proven).
// Each out element written once by a fixed wave -> deterministic.
// n>64: rare slow path (in-loop gathers, drains staging, correct).

constexpr int Bsz  = 2048;
constexpr int Ccnt = 64;
constexpr int INF  = 512;
constexpr int OUTF = 512;
constexpr int THREADS = 256;   // 4 waves = up to 4 sample-groups
constexpr int OT  = 16;        // out rows per staged tile
constexpr int TPB = 4;         // consecutive tiles per block
constexpr int NBUF = 2;        // staging depth
constexpr int NBLK = Ccnt * (OUTF / (OT * TPB));   // 512

typedef __attribute__((ext_vector_type(8))) short bf16x8;
typedef __attribute__((ext_vector_type(4))) float f32x4;

#if __has_builtin(__builtin_amdgcn_cvt_pk_bf16_f32)
typedef __attribute__((ext_vector_type(2))) __bf16 bf16x2_t;
__device__ __forceinline__ int cvt2i(float a, float b) {
    union { bf16x2_t v; int i; } u;
    u.v = __builtin_amdgcn_cvt_pk_bf16_f32(a, b);
    return u.i;
}
#else
__device__ __forceinline__ unsigned f2bf(float f) {
    union { float f; unsigned u; } v; v.f = f;
    return (v.u + 0x7FFFu + ((v.u >> 16) & 1u)) >> 16;   // RNE
}
__device__ __forceinline__ int cvt2i(float a, float b) {
    return (int)(f2bf(a) | (f2bf(b) << 16));
}
#endif

__device__ __forceinline__ bf16x8 cvt8(float4 a, float4 b) {
    union { bf16x8 v; int i[4]; } u;
    u.i[0] = cvt2i(a.x, a.y);
    u.i[1] = cvt2i(a.z, a.w);
    u.i[2] = cvt2i(b.x, b.y);
    u.i[3] = cvt2i(b.z, b.w);
    return u.v;
}

// async 16B/lane global -> LDS (dest = wave-uniform base + lane*16)
__device__ __forceinline__ void gld_lds16(const float* g, float* l) {
    __builtin_amdgcn_global_load_lds(
        (const __attribute__((address_space(1))) float*)g,
        (__attribute__((address_space(3))) float*)l, 16, 0, 0);
}

// workgroup barrier that does NOT touch vmcnt (keeps staging in flight)
__device__ __forceinline__ void barrier_lgkm() {
    asm volatile("s_waitcnt lgkmcnt(0)" ::: "memory");
    __builtin_amdgcn_s_barrier();
    asm volatile("" ::: "memory");
}

// counted-vmcnt barriers: oldest stage landed, newer ops keep flying
__device__ __forceinline__ void vm8_barrier() {
    asm volatile("s_waitcnt vmcnt(8)" ::: "memory");
    __builtin_amdgcn_sched_barrier(0);
    __builtin_amdgcn_s_barrier();
    asm volatile("" ::: "memory");
}
__device__ __forceinline__ void vm0_barrier() {
    asm volatile("s_waitcnt vmcnt(0)" ::: "memory");
    __builtin_amdgcn_sched_barrier(0);
    __builtin_amdgcn_s_barrier();
    asm volatile("" ::: "memory");
}

// stage one 16x512 f32 tile (contiguous 32KB) into LDS, 8 x 1KB insts/wave.
// Element (r,k) lands at dst[r*512 + (((k>>2) ^ (r&7)))*4 + (k&3)] (16B-
// granule XOR swizzle applied on the SOURCE side within 128B lines ->
// coalescing identical to a linear copy; reads de-swizzle with same XOR).
__device__ __forceinline__ void stage_tile(const float* wt, float* dst,
                                           int wave, int lane) {
#pragma unroll
    for (int i = 0; i < 8; ++i) {
        const int inst = wave * 8 + i;
        const int r = inst >> 1;
        const int h = inst & 1;
        const int p = r & 7;
        const float* src = wt + (size_t)r * INF + (h * 64 + (lane ^ p)) * 4;
        gld_lds16(src, dst + inst * 256);
    }
}

__global__ __launch_bounds__(THREADS, 2)
void switching_linear_kernel(const float* __restrict__ x,
                             const int* __restrict__ idx,
                             const float* __restrict__ w,
                             float* __restrict__ out) {
    __shared__ float Wl[NBUF][OT * INF];    // 64 KB double-buffered W tile
    __shared__ unsigned short list[Bsz];    // 4 KB
    __shared__ int ls_n;

    const int tid  = threadIdx.x;
    const int wave = tid >> 6;
    const int lane = tid & 63;

    // XCD-bijective swizzle: the 8 blocks of a class land on one XCD
    const int bid   = ((int)blockIdx.x & 7) * (NBLK / 8) + ((int)blockIdx.x >> 3);
    const int c     = bid >> 3;                 // class
    const int obase = (bid & 7) * (OT * TPB);   // first of 64 contiguous rows

    if (tid == 0) ls_n = 0;
    __syncthreads();   // nothing in flight yet

    // ---- idx scan + list build ----
    int my[8];
#pragma unroll
    for (int i = 0; i < 8; ++i) my[i] = idx[tid + i * THREADS];
#pragma unroll
    for (int i = 0; i < 8; ++i)
        if (my[i] == c) list[atomicAdd(&ls_n, 1)] = (unsigned short)(tid + i * THREADS);

    __syncthreads();   // list complete (drains idx loads; nothing else)
    const int n = ls_n;
    if (n == 0) return;             // uniform; nothing in flight

    const int mrow = lane & 15;   // sample-in-group / C col
    const int quad = lane >> 4;   // k sub-segment / C row group
    const int p    = mrow & 7;
    const float* wc = w + (size_t)c * OUTF * INF + (size_t)obase * INF;

    const int ng0    = (n >= 64) ? 4 : ((n + 15) >> 4);
    const bool active = (wave < ng0);           // wave owns group `wave`
    const int s_my   = wave * 16 + mrow;
    const int sc     = s_my < n ? s_my : n - 1;

    // ---- prologue: gathers FIRST (oldest in FIFO), then both stages ----
    float4 raw[32];                 // full-K x row piece for this lane
    if (active) {
        const float* bp = x + (size_t)list[sc] * INF + quad * 8;
#pragma unroll
        for (int kk = 0; kk < 16; ++kk) {
            raw[2 * kk]     = *(const float4*)(bp + kk * 32);
            raw[2 * kk + 1] = *(const float4*)(bp + kk * 32 + 4);
        }
    }
    __builtin_amdgcn_sched_barrier(0);   // pin: gathers precede stage issues

    stage_tile(wc,                    Wl[0], wave, lane);   // stage(0)
    stage_tile(wc + (size_t)OT * INF, Wl[1], wave, lane);   // stage(1)

    asm volatile("s_waitcnt vmcnt(16)" ::: "memory");  // gathers landed;
    __builtin_amdgcn_sched_barrier(0);                 // both stages flying

    bf16x8 xf[16];                  // full-K x fragments, reused by all tiles
    if (active) {
#pragma unroll
        for (int kk = 0; kk < 16; ++kk)
            xf[kk] = cvt8(raw[2 * kk], raw[2 * kk + 1]);
    }

    vm8_barrier();   // stage(0) landed block-wide; stage(1) keeps flying

    for (int ot = 0; ot < TPB; ++ot) {
        const float* Wb = Wl[ot & 1];
        const int o0 = obase + ot * OT;

        // ---- full-K MFMA for this wave's group; no cross-wave reduce ----
        if (active) {
            f32x4 acc = (f32x4){0.f, 0.f, 0.f, 0.f};
#pragma unroll
            for (int kk = 0; kk < 16; ++kk) {
                const int gb = kk * 8 + quad * 2;   // granule index in row
                float4 a0 = *(const float4*)&Wb[mrow * INF + ((gb)     ^ p) * 4];
                float4 a1 = *(const float4*)&Wb[mrow * INF + ((gb + 1) ^ p) * 4];
                acc = __builtin_amdgcn_mfma_f32_16x16x32_bf16(
                          cvt8(a0, a1), xf[kk], acc, 0, 0, 0);
            }
            if (s_my < n) {
                float* dst = out + (size_t)list[s_my] * OUTF + o0 + quad * 4;
                *(float4*)dst = make_float4(acc[0], acc[1], acc[2], acc[3]);
            }
        }

        // ---- rare slow path: chunks beyond 64 samples (gathers in-loop) ----
        for (int s0 = 64; s0 < n; s0 += 64) {
            if (s0 + wave * 16 < n) {            // this wave's group exists
                const int s2  = s0 + wave * 16 + mrow;
                const int sc2 = s2 < n ? s2 : n - 1;
                const float* bp2 = x + (size_t)list[sc2] * INF + quad * 8;
                f32x4 acc = (f32x4){0.f, 0.f, 0.f, 0.f};
#pragma unroll
                for (int kk = 0; kk < 16; ++kk) {
                    const int gb = kk * 8 + quad * 2;
                    float4 a0 = *(const float4*)&Wb[mrow * INF + ((gb)     ^ p) * 4];
                    float4 a1 = *(const float4*)&Wb[mrow * INF + ((gb + 1) ^ p) * 4];
                    float4 b0 = *(const float4*)(bp2 + kk * 32);
                    float4 b1 = *(const float4*)(bp2 + kk * 32 + 4);
                    acc = __builtin_amdgcn_mfma_f32_16x16x32_bf16(
                              cvt8(a0, a1), cvt8(b0, b1), acc, 0, 0, 0);
                }
                if (s2 < n) {
                    float* dst = out + (size_t)list[s2] * OUTF + o0 + quad * 4;
                    *(float4*)dst = make_float4(acc[0], acc[1], acc[2], acc[3]);
                }
            }
        }

        // ---- buffer handoff: 2 barriers per tile total ----
        if (ot + 2 < TPB) {
            barrier_lgkm();   // all waves' ds_reads of B[ot&1] complete
            stage_tile(wc + (size_t)((ot + 2) * OT) * INF, Wl[ot & 1],
                       wave, lane);
        }
        if (ot + 1 < TPB) {
            if (ot + 2 < TPB) vm8_barrier();   // stage(ot+1) landed; (ot+2) flies
            else              vm0_barrier();   // final stage: full drain
        }
    }
}

extern "C" void kernel_launch(void* const* d_in, const int* in_sizes, int n_in,
                              void* d_out, int out_size, void* d_ws, size_t ws_size,
                              hipStream_t stream) {
    const float* x   = (const float*)d_in[0];
    const int*   idx = (const int*)d_in[1];
    const float* w   = (const float*)d_in[2];
    float* out = (float*)d_out;

    switching_linear_kernel<<<dim3(NBLK), dim3(THREADS), 0, stream>>>(x, idx, w, out);
}

// Round 8
// 101.915 us; speedup vs baseline: 1.0744x; 1.0440x over previous
//
#include <hip/hip_runtime.h>

// out[b,o] = sum_k w[idx[b],o,k] * x[b,k];  B=2048, C=64, IN=OUT=512.
//
// r14: r13 (wave-owns-group, no reduce) regressed +4us -> only ~2 waves
// active, 16-deep dependent MFMA chain, less TLP. r11's K-split+reduce
// structure restored. New change: STAGES-BEFORE-SCAN. W staging doesn't
// need the sample list -- only x-gathers do. Issue stage(0)+stage(1) at
// t~0 (64KB in flight immediately); the idx-scan's data-wait drains them
// via the vmcnt FIFO, but the HBM pipe is BUSY during that wait (vs ~1.5us
// idle in r11). The list __syncthreads doubles as the block-wide "Wl
// valid" fence (each wave drained its own stage ops before it). Prologue
// vm choreography gone; tile loop starts with both buffers landed:
//   ot=0: compute+reduce, stage(2)->Wl[0]; NO boundary barrier;
//   ot=1: compute+reduce, stage(3)->Wl[1]; vm8_barrier (stage2 landed
//         EXACT: stores are older than stage3 in FIFO -> count clean);
//   ot=2: compute+reduce; vm0_barrier; ot=3: compute+reduce.
// Scan vectorized (2 x int4). List order changes (atomic order) but out
// values are list-position-independent -> deterministic.
// Rest = r11: grid 512 (2 blocks/CU), 128KB W stream/block, source-side
// 16B-granule XOR swizzle, XCD-bijective swizzle, gathers->cvt xf in
// regs, lgkm-only reduce barriers, rare n>32 / n>64 slow paths.

constexpr int Bsz  = 2048;
constexpr int Ccnt = 64;
constexpr int INF  = 512;
constexpr int OUTF = 512;
constexpr int THREADS = 256;   // 4 waves = 4 K-quarters
constexpr int OT  = 16;        // out rows per staged tile
constexpr int TPB = 4;         // consecutive tiles per block
constexpr int NBUF = 2;        // staging depth
constexpr int NBLK = Ccnt * (OUTF / (OT * TPB));   // 512

typedef __attribute__((ext_vector_type(8))) short bf16x8;
typedef __attribute__((ext_vector_type(4))) float f32x4;

#if __has_builtin(__builtin_amdgcn_cvt_pk_bf16_f32)
typedef __attribute__((ext_vector_type(2))) __bf16 bf16x2_t;
__device__ __forceinline__ int cvt2i(float a, float b) {
    union { bf16x2_t v; int i; } u;
    u.v = __builtin_amdgcn_cvt_pk_bf16_f32(a, b);
    return u.i;
}
#else
__device__ __forceinline__ unsigned f2bf(float f) {
    union { float f; unsigned u; } v; v.f = f;
    return (v.u + 0x7FFFu + ((v.u >> 16) & 1u)) >> 16;   // RNE
}
__device__ __forceinline__ int cvt2i(float a, float b) {
    return (int)(f2bf(a) | (f2bf(b) << 16));
}
#endif

__device__ __forceinline__ bf16x8 cvt8(float4 a, float4 b) {
    union { bf16x8 v; int i[4]; } u;
    u.i[0] = cvt2i(a.x, a.y);
    u.i[1] = cvt2i(a.z, a.w);
    u.i[2] = cvt2i(b.x, b.y);
    u.i[3] = cvt2i(b.z, b.w);
    return u.v;
}

// async 16B/lane global -> LDS (dest = wave-uniform base + lane*16)
__device__ __forceinline__ void gld_lds16(const float* g, float* l) {
    __builtin_amdgcn_global_load_lds(
        (const __attribute__((address_space(1))) float*)g,
        (__attribute__((address_space(3))) float*)l, 16, 0, 0);
}

// workgroup barrier that does NOT touch vmcnt (keeps staging in flight)
__device__ __forceinline__ void barrier_lgkm() {
    asm volatile("s_waitcnt lgkmcnt(0)" ::: "memory");
    __builtin_amdgcn_s_barrier();
    asm volatile("" ::: "memory");
}

// counted-vmcnt barriers: oldest ops landed, newest 8 keep flying
__device__ __forceinline__ void vm8_barrier() {
    asm volatile("s_waitcnt vmcnt(8)" ::: "memory");
    __builtin_amdgcn_sched_barrier(0);
    __builtin_amdgcn_s_barrier();
    asm volatile("" ::: "memory");
}
__device__ __forceinline__ void vm0_barrier() {
    asm volatile("s_waitcnt vmcnt(0)" ::: "memory");
    __builtin_amdgcn_sched_barrier(0);
    __builtin_amdgcn_s_barrier();
    asm volatile("" ::: "memory");
}

// stage one 16x512 f32 tile (contiguous 32KB) into LDS, 8 x 1KB insts/wave.
// Element (r,k) lands at dst[r*512 + (((k>>2) ^ (r&7)))*4 + (k&3)] (16B-
// granule XOR swizzle applied on the SOURCE side within 128B lines ->
// coalescing identical to a linear copy; reads de-swizzle with same XOR).
__device__ __forceinline__ void stage_tile(const float* wt, float* dst,
                                           int wave, int lane) {
#pragma unroll
    for (int i = 0; i < 8; ++i) {
        const int inst = wave * 8 + i;
        const int r = inst >> 1;
        const int h = inst & 1;
        const int p = r & 7;
        const float* src = wt + (size_t)r * INF + (h * 64 + (lane ^ p)) * 4;
        gld_lds16(src, dst + inst * 256);
    }
}

// cross-wave K-reduce + store, rounds of 2 groups (fixed order ->
// deterministic). lgkm-only barriers: never drains in-flight staging.
__device__ __forceinline__ void kreduce_store(
        const f32x4* acc, int ng, int s0, int n, int o0,
        int wave, int lane, int mrow, int quad,
        const unsigned short* list, float (*red)[3][4][64],
        float* __restrict__ out) {
#pragma unroll
    for (int r0 = 0; r0 < 4; r0 += 2) {
        if (r0 < ng) {                       // uniform across block
            if (wave != 0) {
#pragma unroll
                for (int g = 0; g < 2; ++g) {
                    if (r0 + g < ng) {
#pragma unroll
                        for (int j = 0; j < 4; ++j)
                            red[g][wave - 1][j][lane] = acc[r0 + g][j];
                    }
                }
            }
            barrier_lgkm();
            if (wave == 0) {
#pragma unroll
                for (int g = 0; g < 2; ++g) {
                    if (r0 + g < ng) {
                        const int s = s0 + (r0 + g) * 16 + mrow;
                        if (s < n) {
                            f32x4 a = acc[r0 + g];
#pragma unroll
                            for (int wv2 = 0; wv2 < 3; ++wv2)
#pragma unroll
                                for (int j = 0; j < 4; ++j)
                                    a[j] += red[g][wv2][j][lane];
                            float* dst = out + (size_t)list[s] * OUTF
                                             + o0 + quad * 4;
                            *(float4*)dst = make_float4(a[0], a[1], a[2], a[3]);
                        }
                    }
                }
            }
            barrier_lgkm();                  // red reusable next round
        }
    }
}

__global__ __launch_bounds__(THREADS, 2)
void switching_linear_kernel(const float* __restrict__ x,
                             const int* __restrict__ idx,
                             const float* __restrict__ w,
                             float* __restrict__ out) {
    __shared__ float Wl[NBUF][OT * INF];    // 64 KB double-buffered W tile
    __shared__ unsigned short list[Bsz];    // 4 KB
    __shared__ int ls_n;
    __shared__ float red[2][3][4][64];      // 6 KB (rounds of 2 groups)

    const int tid  = threadIdx.x;
    const int wave = tid >> 6;
    const int lane = tid & 63;

    // XCD-bijective swizzle: the 8 blocks of a class land on one XCD
    const int bid   = ((int)blockIdx.x & 7) * (NBLK / 8) + ((int)blockIdx.x >> 3);
    const int c     = bid >> 3;                 // class
    const int obase = (bid & 7) * (OT * TPB);   // first of 64 contiguous rows

    if (tid == 0) ls_n = 0;
    __syncthreads();   // nothing in flight yet

    const float* wc = w + (size_t)c * OUTF * INF + (size_t)obase * INF;

    // ---- W stream starts at t~0: stages need no list ----
    stage_tile(wc,                    Wl[0], wave, lane);   // stage(0)
    stage_tile(wc + (size_t)OT * INF, Wl[1], wave, lane);   // stage(1)
    __builtin_amdgcn_sched_barrier(0);   // pin: stages precede idx loads

    // ---- idx scan (2 x int4) + list build; HBM busy with stages ----
    const int4* idx4 = (const int4*)idx;
    int4 ia = idx4[tid * 2];
    int4 ib = idx4[tid * 2 + 1];
    int my[8] = {ia.x, ia.y, ia.z, ia.w, ib.x, ib.y, ib.z, ib.w};
#pragma unroll
    for (int i = 0; i < 8; ++i)
        if (my[i] == c) list[atomicAdd(&ls_n, 1)] = (unsigned short)(tid * 8 + i);

    // my[] data-wait (FIFO) drained this wave's stage ops; barrier makes
    // Wl[0], Wl[1] valid block-wide AND list complete.
    __syncthreads();
    const int n = ls_n;
    if (n == 0) {   // uniform; drain any straggler state and exit
        asm volatile("s_waitcnt vmcnt(0)" ::: "memory");
        return;
    }

    const int mrow = lane & 15;   // A row / C col
    const int quad = lane >> 4;   // k segment / C row group
    const int k0   = wave * (INF / 4);
    const int p    = mrow & 7;

    const int ng0 = (n >= 64) ? 4 : ((n + 15) >> 4);
    const int ngp = ng0 < 2 ? ng0 : 2;   // common-case groups (n<=32)

    // ---- x gathers + cvt (nothing in flight; plain loads) ----
    bf16x8 xf[4][4];                // chunk-0 x fragments, reused by all tiles
#pragma unroll
    for (int g = 0; g < 2; ++g) {
        if (g < ngp) {
            const int s  = g * 16 + mrow;
            const int sc = s < n ? s : n - 1;
            const float* bp = x + (size_t)list[sc] * INF + k0 + quad * 8;
#pragma unroll
            for (int i = 0; i < 4; ++i) {
                float4 b0 = *(const float4*)(bp + i * 32);
                float4 b1 = *(const float4*)(bp + i * 32 + 4);
                xf[g][i] = cvt8(b0, b1);
            }
        }
    }
    if (ng0 > 2) {   // rare (n>32)
#pragma unroll
        for (int g = 2; g < 4; ++g) {
            if (g < ng0) {
                const int s  = g * 16 + mrow;
                const int sc = s < n ? s : n - 1;
                const float* bp = x + (size_t)list[sc] * INF + k0 + quad * 8;
#pragma unroll
                for (int i = 0; i < 4; ++i) {
                    float4 b0 = *(const float4*)(bp + i * 32);
                    float4 b1 = *(const float4*)(bp + i * 32 + 4);
                    xf[g][i] = cvt8(b0, b1);
                }
            }
        }
    }

    for (int ot = 0; ot < TPB; ++ot) {
        const float* Wb = Wl[ot & 1];
        const int o0 = obase + ot * OT;

        // A-fragments for this tile (LDS -> regs, lgkm domain only)
        bf16x8 wf[4];
#pragma unroll
        for (int t = 0; t < 4; ++t) {
            const int gb = (k0 >> 2) + t * 8 + quad * 2;   // granule in row
            float4 a0 = *(const float4*)&Wb[mrow * INF + ((gb)     ^ p) * 4];
            float4 a1 = *(const float4*)&Wb[mrow * INF + ((gb + 1) ^ p) * 4];
            wf[t] = cvt8(a0, a1);
        }

        // ---- chunk 0: pure register MFMA (no vmem -> stages keep flying)
        {
            f32x4 acc[4];
#pragma unroll
            for (int g = 0; g < 4; ++g) acc[g] = (f32x4){0.f, 0.f, 0.f, 0.f};
#pragma unroll
            for (int g = 0; g < 4; ++g) {
                if (g < ng0) {
#pragma unroll
                    for (int i = 0; i < 4; ++i)
                        acc[g] = __builtin_amdgcn_mfma_f32_16x16x32_bf16(
                                     wf[i], xf[g][i], acc[g], 0, 0, 0);
                }
            }
            kreduce_store(acc, ng0, 0, n, o0, wave, lane, mrow, quad,
                          list, red, out);
        }

        // ---- rare slow path: chunks beyond 64 samples (gathers in-loop) ----
        for (int s0 = 64; s0 < n; s0 += 64) {
            const int rem = n - s0;
            const int ng  = rem >= 64 ? 4 : (rem + 15) >> 4;

            f32x4 acc[4];
#pragma unroll
            for (int g = 0; g < 4; ++g) acc[g] = (f32x4){0.f, 0.f, 0.f, 0.f};
#pragma unroll
            for (int g = 0; g < 4; ++g) {
                if (g < ng) {
                    const int s  = s0 + g * 16 + mrow;
                    const int sc = s < n ? s : n - 1;
                    const float* bp = x + (size_t)list[sc] * INF + k0 + quad * 8;
#pragma unroll
                    for (int i = 0; i < 4; ++i) {
                        float4 b0 = *(const float4*)(bp + i * 32);
                        float4 b1 = *(const float4*)(bp + i * 32 + 4);
                        acc[g] = __builtin_amdgcn_mfma_f32_16x16x32_bf16(
                                     wf[i], cvt8(b0, b1), acc[g], 0, 0, 0);
                    }
                }
            }
            kreduce_store(acc, ng, s0, n, o0, wave, lane, mrow, quad,
                          list, red, out);
        }

        // kreduce's final barrier => all waves done reading Wb; B[ot&1] free.
        // Stores precede the stage in FIFO -> counted waits stay EXACT.
        if (ot + 2 < TPB)
            stage_tile(wc + (size_t)((ot + 2) * OT) * INF, Wl[ot & 1],
                       wave, lane);

        // Boundaries: ot=0 -> none (Wl[1] landed since prologue);
        // ot=1 -> vm8 (stores+stage2 done, stage3 flying); ot=2 -> vm0.
        if (ot == 1)      vm8_barrier();
        else if (ot == 2) vm0_barrier();
    }
}

extern "C" void kernel_launch(void* const* d_in, const int* in_sizes, int n_in,
                              void* d_out, int out_size, void* d_ws, size_t ws_size,
                              hipStream_t stream) {
    const float* x   = (const float*)d_in[0];
    const int*   idx = (const int*)d_in[1];
    const float* w   = (const float*)d_in[2];
    float* out = (float*)d_out;

    switching_linear_kernel<<<dim3(NBLK), dim3(THREADS), 0, stream>>>(x, idx, w, out);
}